// Round 6
// baseline (153.642 us; speedup 1.0000x reference)
//
#include <hip/hip_runtime.h>
#include <hip/hip_bf16.h>
#include <cmath>

#define AS1 __attribute__((address_space(1)))
#define AS3 __attribute__((address_space(3)))

#define B_ 8
#define W_LEN_ 1000
#define WP 1024          // W padded; rows >= 1000 are exactly 0 -> lsum pad = +24, subtracted at end
#define E_ 100
#define C_ 50
#define CPAD 64          // UO k-padding (2 x K=32 MFMA steps)
#define K_ 3
#define L_ 18000
#define TL 64            // labels per attn block
#define NLBLK ((L_ + TL - 1) / TL)   // 282
#define CWT 16           // w-positions per conv block
#define NSLOT (K_ * (E_ / 4))        // 75 weight slots
#define LOG2E 1.4426950408889634f

typedef __attribute__((ext_vector_type(8))) short bf16x8;   // 8 bf16 = 4 VGPRs
typedef __attribute__((ext_vector_type(4))) short bf16x4;   // 4 bf16 = 2 VGPRs
typedef __attribute__((ext_vector_type(4))) float f32x4;

static __device__ __forceinline__ void gl_lds16(const void* g, void* l) {
    __builtin_amdgcn_global_load_lds((const AS1 unsigned*)g, (AS3 unsigned*)l, 16, 0, 0);
}
static __device__ __forceinline__ float bf2f(short s) {
    return __uint_as_float(((unsigned)(unsigned short)s) << 16);
}

// ---------------- prep (fused): conv_w pack + U'/O bf16 pack ----------------
// blocks [0,15): conv_w (C,E,K) fp32 -> bf16x4 slots [k*25+i][c]
// blocks [15,...): u_w*log2e / out_w fp32 (L,50) -> bf16 (2,L,64) zero-padded, 4 c per thread
__global__ __launch_bounds__(256) void prep_kernel(
    const float* __restrict__ conv_w,
    const float* __restrict__ u_w, const float* __restrict__ out_w,
    bf16x4* __restrict__ cwTs, bf16x4* __restrict__ UO4)
{
    if (blockIdx.x < 15) {
        int idx = blockIdx.x * 256 + threadIdx.x;
        if (idx >= NSLOT * C_) return;
        int slot = idx / C_;
        int c    = idx % C_;
        int k = slot / (E_ / 4);
        int i = slot % (E_ / 4);
        bf16x4 v;
        #pragma unroll
        for (int q = 0; q < 4; q++) {
            __hip_bfloat16 h = __float2bfloat16(conv_w[((size_t)c * E_ + 4 * i + q) * K_ + k]);
            v[q] = *reinterpret_cast<short*>(&h);
        }
        cwTs[idx] = v;
    } else {
        int idx = (blockIdx.x - 15) * 256 + threadIdx.x;   // (m, l, c4)
        if (idx >= 2 * L_ * (CPAD / 4)) return;
        int c4 = idx & 15;
        int l  = (idx >> 4) % L_;
        int m  = idx / (L_ * 16);
        const float* src = m ? out_w : u_w;
        const float scale = m ? 1.f : LOG2E;
        bf16x4 v;
        #pragma unroll
        for (int q = 0; q < 4; q++) {
            int c = c4 * 4 + q;
            __hip_bfloat16 h = __float2bfloat16(c < C_ ? src[(size_t)l * C_ + c] * scale : 0.f);
            v[q] = *reinterpret_cast<short*>(&h);
        }
        UO4[idx] = v;
    }
}

// ---------------- conv: LDS weights (bf16) + LDS embed rows -> bf16 H (B,WP,64) ----------------
__global__ __launch_bounds__(256) void conv_kernel(
    const int* __restrict__ x,          // (B, W)
    const float* __restrict__ W_embed,  // (V, E)
    const bf16x4* __restrict__ cwTs,    // (NSLOT, C)
    const float* __restrict__ conv_b,   // (C,)
    __hip_bfloat16* __restrict__ H)     // (B, WP, 64)
{
    __shared__ float4 emb_s[(CWT + 2) * (E_ / 4)];   // 18 rows x 25 f4 = 7.2 KB
    __shared__ bf16x4 wS[NSLOT * C_];                // 30 KB

    const int b  = blockIdx.y;
    const int w0 = blockIdx.x * CWT;
    const int tid = threadIdx.x;

    for (int i = tid; i < NSLOT * C_; i += 256) wS[i] = cwTs[i];

    for (int i = tid; i < (CWT + 2) * (E_ / 4); i += 256) {
        int row = i / (E_ / 4);
        int e4  = i % (E_ / 4);
        int ws  = w0 - 1 + row;
        float4 v = make_float4(0.f, 0.f, 0.f, 0.f);
        if ((unsigned)ws < (unsigned)W_LEN_)
            v = ((const float4*)(W_embed + (size_t)x[b * W_LEN_ + ws] * E_))[e4];
        emb_s[i] = v;
    }
    __syncthreads();

    const int c  = tid & 63;
    const int wq = tid >> 6;          // 0..3
    const int cc = (c < C_) ? c : 0;  // dead lanes compute c=0, write 0

    f32x4 acc[4];
    const float bias = conv_b[cc];
    #pragma unroll
    for (int j = 0; j < 4; j++) acc[j] = (f32x4){bias, 0.f, 0.f, 0.f};

    const float4* eb = &emb_s[wq * 4 * (E_ / 4)];

    #pragma unroll 5
    for (int i = 0; i < E_ / 4; i++) {
        bf16x4 kb0 = wS[i * C_ + cc];
        bf16x4 kb1 = wS[(25 + i) * C_ + cc];
        bf16x4 kb2 = wS[(50 + i) * C_ + cc];
        float4 k0 = make_float4(bf2f(kb0[0]), bf2f(kb0[1]), bf2f(kb0[2]), bf2f(kb0[3]));
        float4 k1 = make_float4(bf2f(kb1[0]), bf2f(kb1[1]), bf2f(kb1[2]), bf2f(kb1[3]));
        float4 k2 = make_float4(bf2f(kb2[0]), bf2f(kb2[1]), bf2f(kb2[2]), bf2f(kb2[3]));
        float4 e0 = eb[i],       e1 = eb[25 + i],  e2 = eb[50 + i];
        float4 e3 = eb[75 + i],  e4 = eb[100 + i], e5 = eb[125 + i];
        acc[0].x += e0.x*k0.x + e1.x*k1.x + e2.x*k2.x;
        acc[0].y += e0.y*k0.y + e1.y*k1.y + e2.y*k2.y;
        acc[0].z += e0.z*k0.z + e1.z*k1.z + e2.z*k2.z;
        acc[0].w += e0.w*k0.w + e1.w*k1.w + e2.w*k2.w;
        acc[1].x += e1.x*k0.x + e2.x*k1.x + e3.x*k2.x;
        acc[1].y += e1.y*k0.y + e2.y*k1.y + e3.y*k2.y;
        acc[1].z += e1.z*k0.z + e2.z*k1.z + e3.z*k2.z;
        acc[1].w += e1.w*k0.w + e2.w*k1.w + e3.w*k2.w;
        acc[2].x += e2.x*k0.x + e3.x*k1.x + e4.x*k2.x;
        acc[2].y += e2.y*k0.y + e3.y*k1.y + e4.y*k2.y;
        acc[2].z += e2.z*k0.z + e3.z*k1.z + e4.z*k2.z;
        acc[2].w += e2.w*k0.w + e3.w*k1.w + e4.w*k2.w;
        acc[3].x += e3.x*k0.x + e4.x*k1.x + e5.x*k2.x;
        acc[3].y += e3.y*k0.y + e4.y*k1.y + e5.y*k2.y;
        acc[3].z += e3.z*k0.z + e4.z*k1.z + e5.z*k2.z;
        acc[3].w += e3.w*k0.w + e4.w*k1.w + e5.w*k2.w;
    }

    #pragma unroll
    for (int j = 0; j < 4; j++) {
        int w = w0 + wq * 4 + j;
        float v = 0.f;
        if (c < C_ && w < W_LEN_)
            v = tanhf((acc[j].x + acc[j].z) + (acc[j].y + acc[j].w));
        H[((size_t)b * WP + w) * 64 + c] = __float2bfloat16(v);
    }
}

// ---------------- attn: barrier-free dual-GEMM + fused softmax-pool ----------------
// Grid (NLBLK, B), 128 threads = 2 independent waves. Wave ni owns w-half [ni*32, ni*32+32)
// of each 64-w tile: stages its own XOR-swizzled LDS half (global_load_lds, per-lane src
// addr carries the swizzle) and reads only its own rows -> NO __syncthreads in main loop.
// Swizzle: row r (128 B = 8 chunks of 16 B), logical chunk q stored at physical (q+r)&7.
__global__ __launch_bounds__(128) void attn_kernel(
    const __hip_bfloat16* __restrict__ H,   // (B, WP, 64)
    const __hip_bfloat16* __restrict__ UO,  // (2, L, CPAD); U pre-scaled by log2e
    const float* __restrict__ out_b,        // (L,)
    float* __restrict__ out)                // (B, L)
{
    __shared__ __hip_bfloat16 Hs[2][2][32 * 64];   // [ni][buf][row*64+c] 16 KB
    __shared__ float2 red[2][TL];

    const int b  = blockIdx.y;
    const int l0 = blockIdx.x * TL;
    const int tid  = threadIdx.x;
    const int lane = tid & 63;
    const int ni   = tid >> 6;
    const int col = lane & 15, quad = lane >> 4;

    // A-fragments: 4 label-tiles of 16, loop-invariant
    bf16x8 Uf[4][2], Of[4][2];
    #pragma unroll
    for (int mt = 0; mt < 4; mt++) {
        int l = l0 + mt * 16 + col;
        if (l >= L_) l = L_ - 1;                       // clamp; result discarded
        const __hip_bfloat16* up = UO + (size_t)l * CPAD + quad * 8;
        const __hip_bfloat16* op = up + (size_t)L_ * CPAD;
        #pragma unroll
        for (int st = 0; st < 2; st++) {
            Uf[mt][st] = *(const bf16x8*)(up + st * 32);
            Of[mt][st] = *(const bf16x8*)(op + st * 32);
        }
    }

    f32x4 lsum[4], num[4];
    #pragma unroll
    for (int mt = 0; mt < 4; mt++) { lsum[mt] = (f32x4){0,0,0,0}; num[mt] = (f32x4){0,0,0,0}; }
    const f32x4 zero = {0.f, 0.f, 0.f, 0.f};

    // per-lane swizzled staging source offsets (elements), s = 0..3
    int goff[4];
    #pragma unroll
    for (int s = 0; s < 4; s++) {
        int p  = s * 64 + lane;       // physical chunk in wave's 32x64 half
        int r  = p >> 3;              // local row
        int pc = p & 7;               // physical chunk-in-row
        int q  = (pc - r) & 7;        // logical chunk stored here
        goff[s] = (ni * 32 + r) * 64 + q * 8;
    }

    const __hip_bfloat16* Hb = H + (size_t)b * WP * 64;
    char* lbase = (char*)&Hs[ni][0][0];

    // stage tile 0 into buf 0
    #pragma unroll
    for (int s = 0; s < 4; s++)
        gl_lds16((const char*)(Hb + goff[s]), lbase + s * 1024 + lane * 16);

    #pragma unroll 1
    for (int wt = 0; wt < WP; wt += 64) {
        const int cur = (wt >> 6) & 1;

        if (wt + 64 < WP) {
            const __hip_bfloat16* g = Hb + (size_t)(wt + 64) * 64;
            char* l = lbase + (cur ^ 1) * 4096;
            #pragma unroll
            for (int s = 0; s < 4; s++)
                gl_lds16((const char*)(g + goff[s]), l + s * 1024 + lane * 16);
        }

        // B-frags from own swizzled half: row = nt*16+col, chunk = quad+4st -> phys (q+r)&7
        bf16x8 Bc[2][2];
        #pragma unroll
        for (int nt = 0; nt < 2; nt++) {
            int r = nt * 16 + col;
            #pragma unroll
            for (int st = 0; st < 2; st++)
                Bc[nt][st] = *(const bf16x8*)(&Hs[ni][cur][r * 64 + ((quad + 4 * st + r) & 7) * 8]);
        }

        #pragma unroll
        for (int nt = 0; nt < 2; nt++) {
            #pragma unroll
            for (int mt = 0; mt < 4; mt++) {
                f32x4 S = __builtin_amdgcn_mfma_f32_16x16x32_bf16(Uf[mt][0], Bc[nt][0], zero, 0, 0, 0);
                S       = __builtin_amdgcn_mfma_f32_16x16x32_bf16(Uf[mt][1], Bc[nt][1], S,    0, 0, 0);
                f32x4 T = __builtin_amdgcn_mfma_f32_16x16x32_bf16(Of[mt][0], Bc[nt][0], zero, 0, 0, 0);
                T       = __builtin_amdgcn_mfma_f32_16x16x32_bf16(Of[mt][1], Bc[nt][1], T,    0, 0, 0);
                #pragma unroll
                for (int r = 0; r < 4; r++) {
                    float p = __builtin_amdgcn_exp2f(S[r]);   // U pre-scaled by log2e
                    lsum[mt][r] += p;
                    num [mt][r] = fmaf(p, T[r], num[mt][r]);
                }
            }
        }
    }

    // reduce 16 w-cols (lane bits 0-3); col==0 lanes hold label mt*16+quad*4+r
    #pragma unroll
    for (int mt = 0; mt < 4; mt++) {
        #pragma unroll
        for (int r = 0; r < 4; r++) {
            float ls = lsum[mt][r], nm = num[mt][r];
            #pragma unroll
            for (int d = 1; d < 16; d <<= 1) {
                ls += __shfl_xor(ls, d, 64);
                nm += __shfl_xor(nm, d, 64);
            }
            if (col == 0)
                red[ni][mt * 16 + quad * 4 + r] = make_float2(ls, nm);
        }
    }
    __syncthreads();

    if (tid < TL) {
        int l = l0 + tid;
        if (l < L_) {
            float2 p0 = red[0][tid], p1 = red[1][tid];
            float z = (p0.y + p1.y) / (p0.x + p1.x - (float)(WP - W_LEN_)) + out_b[l];
            out[(size_t)b * L_ + l] = 1.f / (1.f + __expf(-z));
        }
    }
}

extern "C" void kernel_launch(void* const* d_in, const int* in_sizes, int n_in,
                              void* d_out, int out_size, void* d_ws, size_t ws_size,
                              hipStream_t stream) {
    const int*   x       = (const int*)  d_in[0];
    const float* W_embed = (const float*)d_in[1];
    const float* conv_w  = (const float*)d_in[2];
    const float* conv_b  = (const float*)d_in[3];
    const float* u_w     = (const float*)d_in[4];
    const float* out_w   = (const float*)d_in[5];
    const float* out_b   = (const float*)d_in[6];
    float* out = (float*)d_out;

    char* ws = (char*)d_ws;
    __hip_bfloat16* H  = (__hip_bfloat16*)ws;                 // 8*1024*64*2 = 1,048,576 B
    __hip_bfloat16* UO = (__hip_bfloat16*)(ws + 1048576);     // 2*18000*64*2 = 4,608,000 B
    bf16x4*       cwTs = (bf16x4*)(ws + 1048576 + 4608000);   // 30,000 B

    {
        const int uo_blocks = (2 * L_ * (CPAD / 4) + 255) / 256;   // 2250
        prep_kernel<<<dim3(15 + uo_blocks), 256, 0, stream>>>(conv_w, u_w, out_w,
                                                              cwTs, (bf16x4*)UO);
    }
    {
        dim3 grid(WP / CWT, B_);
        conv_kernel<<<grid, 256, 0, stream>>>(x, W_embed, cwTs, conv_b, H);
    }
    {
        dim3 grid(NLBLK, B_);
        attn_kernel<<<grid, 128, 0, stream>>>(H, UO, out_b, out);
    }
}